// Round 13
// baseline (313.106 us; speedup 1.0000x reference)
//
#include <hip/hip_runtime.h>
#include <hip/hip_bf16.h>

#define B_ 4
#define T_ 2048
#define HS_ 1024
#define H_ 16
#define R_ 16
#define D_ 64
#define BT_ (B_*T_)          // 8192
#define NC_ 3328             // q(1024) k(1024) v(1024) g(256)
#define CHUNK_ 64
#define NCHUNK_ (T_/CHUNK_)  // 32

typedef __attribute__((ext_vector_type(8))) short short8;
typedef __attribute__((ext_vector_type(4))) float f32x4;

__device__ __forceinline__ float b2f(ushort u){
    union{unsigned int i; float f;} v; v.i = ((unsigned int)u) << 16; return v.f;
}
__device__ __forceinline__ ushort f2b(float f){
    __hip_bfloat16 h = __float2bfloat16(f);
    return *reinterpret_cast<ushort*>(&h);
}
__device__ __forceinline__ float sigm(float x){ return 1.f/(1.f+expf(-x)); }

// async global->LDS, 16B per lane; lds dest is wave-uniform base + lane*16
__device__ __forceinline__ void gl_lds16(const void* g, void* l){
    __builtin_amdgcn_global_load_lds((const __attribute__((address_space(1))) void*)g,
                                     (__attribute__((address_space(3))) void*)l,
                                     16, 0, 0);
}

// ---------- merged prep kernel ----------
__global__ void k_prep(const float* __restrict__ x,
                       const float* __restrict__ qw, const float* __restrict__ kw,
                       const float* __restrict__ vw, const float* __restrict__ gw,
                       const float* __restrict__ outw,
                       ushort* __restrict__ xbf, ushort* __restrict__ wcat,
                       ushort* __restrict__ owbf,
                       float* __restrict__ cosT, float* __restrict__ sinT){
    int bid = blockIdx.x;
    if(bid < 8192){
        int i = bid*256 + threadIdx.x;
        float4 v = ((const float4*)x)[i];
        ushort4 o; o.x=f2b(v.x); o.y=f2b(v.y); o.z=f2b(v.z); o.w=f2b(v.w);
        ((ushort4*)xbf)[i] = o;
    } else if(bid < 11520){
        int i = (bid-8192)*256 + threadIdx.x;
        int e = i*4;
        int row = e >> 10, col = e & 1023;
        const float* src;
        if      (row < 1024) src = qw + (size_t)row*1024 + col;
        else if (row < 2048) src = kw + (size_t)(row-1024)*1024 + col;
        else if (row < 3072) src = vw + (size_t)(row-2048)*1024 + col;
        else                 src = gw + (size_t)(row-3072)*1024 + col;
        float4 v = *(const float4*)src;
        ushort4 o; o.x=f2b(v.x); o.y=f2b(v.y); o.z=f2b(v.z); o.w=f2b(v.w);
        ((ushort4*)wcat)[i] = o;
    } else if(bid < 12544){
        int i = (bid-11520)*256 + threadIdx.x;
        float4 v = ((const float4*)outw)[i];
        ushort4 o; o.x=f2b(v.x); o.y=f2b(v.y); o.z=f2b(v.z); o.w=f2b(v.w);
        ((ushort4*)owbf)[i] = o;
    } else {
        int i = (bid-12544)*256 + threadIdx.x;   // 65536 = 2048*32
        int t = i >> 5, f = i & 31;
        float inv = powf(10000.f, -(float)f/32.f);
        float a = (float)t * inv;
        cosT[i] = cosf(a);
        sinT[i] = sinf(a);
    }
}

// ---------- 256x128 dbuf bf16 GEMM: C = A @ B^T (R11 config, best measured) ----------
// 8 waves (4M x 2N), per-wave 64x64 output. BK=32. LDS 48KB dbuf.
// Bank rotation (fg+(fr>>1))&3 + inverse-staged source: measured 0 conflicts.
__global__ __launch_bounds__(512, 4) void k_gemm256d(const ushort* __restrict__ A,
                                                     const ushort* __restrict__ Bm,
                                                     ushort* __restrict__ C,
                                                     int K, int ldc){
    __shared__ __align__(16) ushort lds[24576];   // 2 x 12288 ushorts (48KB)
    const int tid  = threadIdx.x;
    const int lane = tid & 63, w = tid >> 6;
    const int fr = lane & 15, fg = lane >> 4;
    const int wm = w >> 1, wn = w & 1;            // 4M x 2N
    const int qa = ((fg + (fr >> 1)) & 3) * 8;    // verified rotation (ushorts)

    // XCD supertile mapping (R5: keeps A-panel resident in XCD L2)
    int mt = gridDim.x;
    int L = blockIdx.y * mt + blockIdx.x;
    int bxi, byi;
    int msub = mt >> 3;
    if((mt & 7) == 0 && msub > 0){
        int xcd = L & 7, c = L >> 3;
        bxi = xcd * msub + (c % msub);
        byi = c / msub;
    } else { bxi = blockIdx.x; byi = blockIdx.y; }
    const long arow0 = (long)bxi * 256;
    const long brow0 = (long)byi * 128;

    const int srow = tid >> 2;
    const int scol = ((((tid & 3) - (tid >> 3)) & 3)) * 8;
    const ushort* gsrc0 = A  + (arow0 +       srow) * (size_t)K + scol;
    const ushort* gsrc1 = A  + (arow0 + 128 + srow) * (size_t)K + scol;
    const ushort* gsrc2 = Bm + (brow0 +       srow) * (size_t)K + scol;

#define STG(t) do{ ushort* _b = &lds[((t)&1)*12288 + w*512];                  \
    gl_lds16(gsrc0 + (size_t)(t)*32, _b);                                     \
    gl_lds16(gsrc1 + (size_t)(t)*32, _b + 4096);                              \
    gl_lds16(gsrc2 + (size_t)(t)*32, _b + 8192); }while(0)

    f32x4 acc[4][4];
#pragma unroll
    for(int m=0;m<4;m++)
#pragma unroll
        for(int n=0;n<4;n++)
            acc[m][n] = (f32x4){0.f,0.f,0.f,0.f};

    const int NT = K >> 5;
    STG(0);
    for(int t=0; t<NT; ++t){
        asm volatile("s_waitcnt vmcnt(0)" ::: "memory");
        __builtin_amdgcn_s_barrier();      // buf[t&1] resident for all waves
        __builtin_amdgcn_sched_barrier(0); // no reads hoisted above
        if(t+1 < NT) STG(t+1);             // WAR-safe: buf[t+1&1] reads done in t-1
        const int sb = (t&1)*12288;
        short8 af[4], bv[4];
#pragma unroll
        for(int mm=0; mm<4; ++mm)
            af[mm] = *(const short8*)&lds[sb + (wm*64 + mm*16 + fr)*32 + qa];
#pragma unroll
        for(int nf=0; nf<4; ++nf)
            bv[nf] = *(const short8*)&lds[sb + 8192 + (wn*64 + nf*16 + fr)*32 + qa];
        __builtin_amdgcn_s_setprio(1);
#pragma unroll
        for(int mm=0; mm<4; ++mm)
#pragma unroll
        for(int nf=0; nf<4; ++nf)
            acc[mm][nf] = __builtin_amdgcn_mfma_f32_16x16x32_bf16(
                af[mm], bv[nf], acc[mm][nf], 0,0,0);
        __builtin_amdgcn_s_setprio(0);
    }
#undef STG

#pragma unroll
    for(int m=0;m<4;m++)
#pragma unroll
        for(int n=0;n<4;n++){
            long col = brow0 + wn*64 + n*16 + fr;
#pragma unroll
            for(int j=0;j<4;j++){
                long row = arow0 + wm*64 + m*16 + fg*4 + j;
                C[row*(size_t)ldc + col] = f2b(acc[m][n][j]);
            }
        }
}

// ---------- RoPE + rank projection + gate (MFMA version) ----------
__global__ __launch_bounds__(256) void k_rope_proj(const ushort* __restrict__ qkvg,
                                                   const float* __restrict__ cosT,
                                                   const float* __restrict__ sinT,
                                                   const float* __restrict__ Wq,
                                                   const float* __restrict__ Wk,
                                                   const float* __restrict__ gb,
                                                   float* __restrict__ qr_s,
                                                   float* __restrict__ gk_s){
    __shared__ __align__(16) ushort lq[64*72], lk[64*72];
    __shared__ __align__(16) ushort wql[16*72], wkl[16*72];
    int tid = threadIdx.x, wid = tid >> 6, lane = tid & 63;
    int bt0 = blockIdx.x * 64;
    int h   = blockIdx.y;

    {
        int row = tid >> 4, seg = tid & 15;
        float4 wq4 = *(const float4*)(Wq + (size_t)h*1024 + row*64 + seg*4);
        float4 wk4 = *(const float4*)(Wk + (size_t)h*1024 + row*64 + seg*4);
        ushort* dq = &wql[row*72 + seg*4];
        ushort* dk = &wkl[row*72 + seg*4];
        dq[0]=f2b(wq4.x); dq[1]=f2b(wq4.y); dq[2]=f2b(wq4.z); dq[3]=f2b(wq4.w);
        dk[0]=f2b(wk4.x); dk[1]=f2b(wk4.y); dk[2]=f2b(wk4.z); dk[3]=f2b(wk4.w);
    }

#pragma unroll
    for(int rep=0; rep<2; ++rep){
        int flat = rep*256 + tid;
        int row = flat >> 3, seg = flat & 7;
        int t = (bt0 + row) & 2047;
        const ushort* base = qkvg + (size_t)(bt0+row)*NC_ + h*64 + seg*8;
        short8 q8 = *(const short8*)base;
        short8 k8 = *(const short8*)(base + 1024);
        float4 cv = *(const float4*)&cosT[t*32 + seg*4];
        float4 sv = *(const float4*)&sinT[t*32 + seg*4];
        float qf[8], kf[8];
#pragma unroll
        for(int j=0;j<8;j++){ qf[j]=b2f((ushort)q8[j]); kf[j]=b2f((ushort)k8[j]); }
        float c4[4] = {cv.x,cv.y,cv.z,cv.w};
        float s4[4] = {sv.x,sv.y,sv.z,sv.w};
        short8 qo, ko;
#pragma unroll
        for(int p=0;p<4;p++){
            float c=c4[p], s=s4[p];
            qo[2*p]   = (short)f2b(qf[2*p]*c - qf[2*p+1]*s);
            qo[2*p+1] = (short)f2b(qf[2*p]*s + qf[2*p+1]*c);
            ko[2*p]   = (short)f2b(kf[2*p]*c - kf[2*p+1]*s);
            ko[2*p+1] = (short)f2b(kf[2*p]*s + kf[2*p+1]*c);
        }
        *(short8*)&lq[row*72 + seg*8] = qo;
        *(short8*)&lk[row*72 + seg*8] = ko;
    }
    __syncthreads();

    int fr = lane & 15, fg = lane >> 4;
    int wrow = wid*16;
    short8 aq0 = *(const short8*)&lq[(wrow+fr)*72 + fg*8];
    short8 aq1 = *(const short8*)&lq[(wrow+fr)*72 + 32 + fg*8];
    short8 ak0 = *(const short8*)&lk[(wrow+fr)*72 + fg*8];
    short8 ak1 = *(const short8*)&lk[(wrow+fr)*72 + 32 + fg*8];
    short8 bq0 = *(const short8*)&wql[fr*72 + fg*8];
    short8 bq1 = *(const short8*)&wql[fr*72 + 32 + fg*8];
    short8 bk0 = *(const short8*)&wkl[fr*72 + fg*8];
    short8 bk1 = *(const short8*)&wkl[fr*72 + 32 + fg*8];
    f32x4 accq = (f32x4){0.f,0.f,0.f,0.f};
    f32x4 acck = (f32x4){0.f,0.f,0.f,0.f};
    accq = __builtin_amdgcn_mfma_f32_16x16x32_bf16(aq0, bq0, accq, 0,0,0);
    accq = __builtin_amdgcn_mfma_f32_16x16x32_bf16(aq1, bq1, accq, 0,0,0);
    acck = __builtin_amdgcn_mfma_f32_16x16x32_bf16(ak0, bk0, acck, 0,0,0);
    acck = __builtin_amdgcn_mfma_f32_16x16x32_bf16(ak1, bk1, acck, 0,0,0);

    int r = fr;
    float gbv = gb[h*16 + r];
#pragma unroll
    for(int j=0;j<4;j++){
        int bt = bt0 + wrow + fg*4 + j;
        int t  = bt & 2047, b = bt >> 11;
        size_t o = (((size_t)(b*16 + h))*2048 + t)*16 + r;
        qr_s[o] = accq[j];
        float gl = b2f(qkvg[(size_t)bt*NC_ + 3072 + h*16 + r]) + gbv;
        gk_s[o] = sigm(gl) * acck[j] * 0.125f;
    }
}

// ---------- fused chunked scan: local states -> LDS carry prefix -> replay ----------
// One block per (b,h): 1024 threads = 16 waves, 2 chunks of 64 per wave.
// Phase A: per-chunk local M (M0=0) -> LDS[ch][r*64+d]  (128KB)
// Phase B: 1024 threads, thread i owns element i=(r*64+d): 32-step prefix
//          S' = S*dec^64 + m, storing state-at-chunk-start back to LDS.
// Phase C: replay chunks with carried start state, emit y. v/gk re-reads are
// L2-hot (per-XCD working set ~3MB < 4MB).
__global__ __launch_bounds__(1024) void k_scan_fused(const ushort* __restrict__ qkvg,
                                                     const float* __restrict__ gk_s,
                                                     const float* __restrict__ qr_s,
                                                     const float* __restrict__ bdl,
                                                     ushort* __restrict__ Ybf){
    __shared__ float Ml[NCHUNK_*1024];   // 128 KB
    int bh = blockIdx.x;                 // b*16 + h
    int b = bh >> 4, h = bh & 15;
    int tid = threadIdx.x, wid = tid >> 6, lane = tid & 63;
    float dec[16];
#pragma unroll
    for(int r=0;r<16;r++) dec[r] = sigm(bdl[h*16+r]);

    // phase A: local chunk states
#pragma unroll
    for(int cc=0; cc<2; ++cc){
        int ch = wid*2 + cc;
        int t0 = ch*CHUNK_;
        const float4*  gk4 = (const float4*)(gk_s + (((size_t)bh)*2048 + t0)*16);
        const ushort*  vp  = qkvg + ((size_t)(b*2048 + t0))*NC_ + 2048 + h*64 + lane;
        float M[16];
#pragma unroll
        for(int r=0;r<16;r++) M[r] = 0.f;
        for(int tt=0; tt<CHUNK_; ++tt){
            float v = b2f(*vp); vp += NC_;
            float4 a0 = gk4[0], a1 = gk4[1], a2 = gk4[2], a3 = gk4[3]; gk4 += 4;
            float gk[16] = {a0.x,a0.y,a0.z,a0.w, a1.x,a1.y,a1.z,a1.w,
                            a2.x,a2.y,a2.z,a2.w, a3.x,a3.y,a3.z,a3.w};
#pragma unroll
            for(int r=0;r<16;r++) M[r] = fmaf(M[r], dec[r], gk[r]*v);
        }
        float* mp = &Ml[ch*1024 + lane];
#pragma unroll
        for(int r=0;r<16;r++) mp[r*64] = M[r];
    }
    __syncthreads();

    // phase B: carry prefix in LDS (thread i owns element i; r = i>>6)
    {
        float dc = powf(dec[tid >> 6], (float)CHUNK_);
        float S = 0.f;
        for(int c=0; c<NCHUNK_; ++c){
            float m = Ml[c*1024 + tid];
            Ml[c*1024 + tid] = S;
            S = fmaf(S, dc, m);
        }
    }
    __syncthreads();

    // phase C: replay with carried start state, emit y
#pragma unroll
    for(int cc=0; cc<2; ++cc){
        int ch = wid*2 + cc;
        int t0 = ch*CHUNK_;
        float M[16];
        const float* sp = &Ml[ch*1024 + lane];
#pragma unroll
        for(int r=0;r<16;r++) M[r] = sp[r*64];
        const float4* gk4 = (const float4*)(gk_s + (((size_t)bh)*2048 + t0)*16);
        const float4* q4  = (const float4*)(qr_s + (((size_t)bh)*2048 + t0)*16);
        const ushort* vp  = qkvg + ((size_t)(b*2048 + t0))*NC_ + 2048 + h*64 + lane;
        ushort*       yp  = Ybf  + ((size_t)(b*2048 + t0))*1024 + h*64 + lane;
        for(int tt=0; tt<CHUNK_; ++tt){
            float v = b2f(*vp); vp += NC_;
            float4 a0 = gk4[0], a1 = gk4[1], a2 = gk4[2], a3 = gk4[3]; gk4 += 4;
            float4 b0 = q4[0],  b1 = q4[1],  b2 = q4[2],  b3 = q4[3];  q4  += 4;
            float gk[16] = {a0.x,a0.y,a0.z,a0.w, a1.x,a1.y,a1.z,a1.w,
                            a2.x,a2.y,a2.z,a2.w, a3.x,a3.y,a3.z,a3.w};
            float qv[16] = {b0.x,b0.y,b0.z,b0.w, b1.x,b1.y,b1.z,b1.w,
                            b2.x,b2.y,b2.z,b2.w, b3.x,b3.y,b3.z,b3.w};
            float y = 0.f;
#pragma unroll
            for(int r=0;r<16;r++){
                M[r] = fmaf(M[r], dec[r], gk[r]*v);
                y    = fmaf(qv[r], M[r], y);
            }
            *yp = f2b(y); yp += 1024;
        }
    }
}

// ---------- residual + LayerNorm ----------
__global__ __launch_bounds__(256) void k_ln(const float* __restrict__ x,
                                            const ushort* __restrict__ O,
                                            const float* __restrict__ ob,
                                            const float* __restrict__ lg,
                                            const float* __restrict__ lb,
                                            float* __restrict__ out){
    __shared__ float red[8];
    int row = blockIdx.x, tid = threadIdx.x;
    float hv[4];
    float sum = 0.f, ssq = 0.f;
#pragma unroll
    for(int k2=0;k2<4;k2++){
        int j = tid + k2*256;
        float v = x[(size_t)row*1024 + j] + b2f(O[(size_t)row*1024 + j]) + ob[j];
        hv[k2] = v; sum += v; ssq += v*v;
    }
#pragma unroll
    for(int off=32; off; off >>= 1){
        sum += __shfl_down(sum, off, 64);
        ssq += __shfl_down(ssq, off, 64);
    }
    int wid = tid >> 6, lane = tid & 63;
    if(lane == 0){ red[wid] = sum; red[4+wid] = ssq; }
    __syncthreads();
    if(tid == 0){
        float s = red[0]+red[1]+red[2]+red[3];
        float q = red[4]+red[5]+red[6]+red[7];
        float mu = s / 1024.f;
        red[0] = mu;
        red[1] = q / 1024.f - mu*mu;
    }
    __syncthreads();
    float mu = red[0];
    float inv = rsqrtf(red[1] + 1e-5f);
#pragma unroll
    for(int k2=0;k2<4;k2++){
        int j = tid + k2*256;
        out[(size_t)row*1024 + j] = (hv[k2]-mu)*inv*lg[j] + lb[j];
    }
}

extern "C" void kernel_launch(void* const* d_in, const int* in_sizes, int n_in,
                              void* d_out, int out_size, void* d_ws, size_t ws_size,
                              hipStream_t stream){
    const float* x    = (const float*)d_in[0];
    const float* q_w  = (const float*)d_in[1];
    const float* k_w  = (const float*)d_in[2];
    const float* v_w  = (const float*)d_in[3];
    const float* Wq   = (const float*)d_in[4];
    const float* Wk   = (const float*)d_in[5];
    const float* g_w  = (const float*)d_in[6];
    const float* g_b  = (const float*)d_in[7];
    const float* bdl  = (const float*)d_in[8];
    const float* outw = (const float*)d_in[9];
    const float* outb = (const float*)d_in[10];
    const float* ln_g = (const float*)d_in[11];
    const float* ln_b = (const float*)d_in[12];
    float* out = (float*)d_out;

    char* ws = (char*)d_ws;
    size_t off = 0;
    ushort* xbf  = (ushort*)(ws + off); off += (size_t)BT_*HS_*2;
    ushort* wcat = (ushort*)(ws + off); off += (size_t)NC_*HS_*2;
    ushort* owbf = (ushort*)(ws + off); off += (size_t)HS_*HS_*2;
    float*  cosT = (float*)(ws + off);  off += (size_t)T_*32*4;
    float*  sinT = (float*)(ws + off);  off += (size_t)T_*32*4;
    ushort* qkvg = (ushort*)(ws + off); off += (size_t)BT_*NC_*2;
    float*  qr_s = (float*)(ws + off);  off += (size_t)BT_*H_*R_*4;
    float*  gk_s = (float*)(ws + off);  off += (size_t)BT_*H_*R_*4;
    ushort* Ybf = xbf;     // xbf dead after GEMM1
    ushort* O   = qkvg;    // qkvg dead after scan

    // merged prep (x cast | wcat build | outw cast | rope table)
    k_prep<<<12800, 256, 0, stream>>>(x, q_w, k_w, v_w, g_w, outw,
                                      xbf, wcat, owbf, cosT, sinT);

    // GEMM1: qkvg[8192][3328] = xbf @ wcat^T   (256x128 dbuf, 32x26=832 blocks)
    k_gemm256d<<<dim3(BT_/256, NC_/128), 512, 0, stream>>>(xbf, wcat, qkvg, HS_, NC_);

    // rope + rank-proj + gate (MFMA)
    k_rope_proj<<<dim3(BT_/64, H_), 256, 0, stream>>>(qkvg, cosT, sinT, Wq, Wk, g_b, qr_s, gk_s);

    // fused chunked scan (local -> LDS carry -> replay)
    k_scan_fused<<<B_*H_, 1024, 0, stream>>>(qkvg, gk_s, qr_s, bdl, Ybf);

    // GEMM2: O[8192][1024] = Ybf @ owbf^T  (32x8=256 blocks)
    k_gemm256d<<<dim3(BT_/256, HS_/128), 512, 0, stream>>>(Ybf, owbf, O, HS_, HS_);

    // residual + LayerNorm
    k_ln<<<BT_, 256, 0, stream>>>(x, O, outb, ln_g, ln_b, out);

    (void)in_sizes; (void)n_in; (void)out_size; (void)ws_size;
}

// Round 14
// 192.090 us; speedup vs baseline: 1.6300x; 1.6300x over previous
//
#include <hip/hip_runtime.h>
#include <hip/hip_bf16.h>

#define B_ 4
#define T_ 2048
#define HS_ 1024
#define H_ 16
#define R_ 16
#define D_ 64
#define BT_ (B_*T_)          // 8192
#define NC_ 3328             // q(1024) k(1024) v(1024) g(256)
#define CHUNK_ 64
#define NCHUNK_ (T_/CHUNK_)  // 32

typedef __attribute__((ext_vector_type(8))) short short8;
typedef __attribute__((ext_vector_type(4))) float f32x4;

__device__ __forceinline__ float b2f(ushort u){
    union{unsigned int i; float f;} v; v.i = ((unsigned int)u) << 16; return v.f;
}
__device__ __forceinline__ ushort f2b(float f){
    __hip_bfloat16 h = __float2bfloat16(f);
    return *reinterpret_cast<ushort*>(&h);
}
__device__ __forceinline__ float sigm(float x){ return 1.f/(1.f+expf(-x)); }

// async global->LDS, 16B per lane; lds dest is wave-uniform base + lane*16
__device__ __forceinline__ void gl_lds16(const void* g, void* l){
    __builtin_amdgcn_global_load_lds((const __attribute__((address_space(1))) void*)g,
                                     (__attribute__((address_space(3))) void*)l,
                                     16, 0, 0);
}

// ---------- merged prep kernel ----------
__global__ void k_prep(const float* __restrict__ x,
                       const float* __restrict__ qw, const float* __restrict__ kw,
                       const float* __restrict__ vw, const float* __restrict__ gw,
                       const float* __restrict__ outw,
                       ushort* __restrict__ xbf, ushort* __restrict__ wcat,
                       ushort* __restrict__ owbf,
                       float* __restrict__ cosT, float* __restrict__ sinT){
    int bid = blockIdx.x;
    if(bid < 8192){
        int i = bid*256 + threadIdx.x;
        float4 v = ((const float4*)x)[i];
        ushort4 o; o.x=f2b(v.x); o.y=f2b(v.y); o.z=f2b(v.z); o.w=f2b(v.w);
        ((ushort4*)xbf)[i] = o;
    } else if(bid < 11520){
        int i = (bid-8192)*256 + threadIdx.x;
        int e = i*4;
        int row = e >> 10, col = e & 1023;
        const float* src;
        if      (row < 1024) src = qw + (size_t)row*1024 + col;
        else if (row < 2048) src = kw + (size_t)(row-1024)*1024 + col;
        else if (row < 3072) src = vw + (size_t)(row-2048)*1024 + col;
        else                 src = gw + (size_t)(row-3072)*1024 + col;
        float4 v = *(const float4*)src;
        ushort4 o; o.x=f2b(v.x); o.y=f2b(v.y); o.z=f2b(v.z); o.w=f2b(v.w);
        ((ushort4*)wcat)[i] = o;
    } else if(bid < 12544){
        int i = (bid-11520)*256 + threadIdx.x;
        float4 v = ((const float4*)outw)[i];
        ushort4 o; o.x=f2b(v.x); o.y=f2b(v.y); o.z=f2b(v.z); o.w=f2b(v.w);
        ((ushort4*)owbf)[i] = o;
    } else {
        int i = (bid-12544)*256 + threadIdx.x;   // 65536 = 2048*32
        int t = i >> 5, f = i & 31;
        float inv = powf(10000.f, -(float)f/32.f);
        float a = (float)t * inv;
        cosT[i] = cosf(a);
        sinT[i] = sinf(a);
    }
}

// ---------- 256x128 dbuf bf16 GEMM: C = A @ B^T (R11 config, best measured) ----------
// 8 waves (4M x 2N), per-wave 64x64 output. BK=32. LDS 48KB dbuf.
// Bank rotation (fg+(fr>>1))&3 + inverse-staged source: measured 0 conflicts.
__global__ __launch_bounds__(512, 4) void k_gemm256d(const ushort* __restrict__ A,
                                                     const ushort* __restrict__ Bm,
                                                     ushort* __restrict__ C,
                                                     int K, int ldc){
    __shared__ __align__(16) ushort lds[24576];   // 2 x 12288 ushorts (48KB)
    const int tid  = threadIdx.x;
    const int lane = tid & 63, w = tid >> 6;
    const int fr = lane & 15, fg = lane >> 4;
    const int wm = w >> 1, wn = w & 1;            // 4M x 2N
    const int qa = ((fg + (fr >> 1)) & 3) * 8;    // verified rotation (ushorts)

    // XCD supertile mapping (R5: keeps A-panel resident in XCD L2)
    int mt = gridDim.x;
    int L = blockIdx.y * mt + blockIdx.x;
    int bxi, byi;
    int msub = mt >> 3;
    if((mt & 7) == 0 && msub > 0){
        int xcd = L & 7, c = L >> 3;
        bxi = xcd * msub + (c % msub);
        byi = c / msub;
    } else { bxi = blockIdx.x; byi = blockIdx.y; }
    const long arow0 = (long)bxi * 256;
    const long brow0 = (long)byi * 128;

    const int srow = tid >> 2;
    const int scol = ((((tid & 3) - (tid >> 3)) & 3)) * 8;
    const ushort* gsrc0 = A  + (arow0 +       srow) * (size_t)K + scol;
    const ushort* gsrc1 = A  + (arow0 + 128 + srow) * (size_t)K + scol;
    const ushort* gsrc2 = Bm + (brow0 +       srow) * (size_t)K + scol;

#define STG(t) do{ ushort* _b = &lds[((t)&1)*12288 + w*512];                  \
    gl_lds16(gsrc0 + (size_t)(t)*32, _b);                                     \
    gl_lds16(gsrc1 + (size_t)(t)*32, _b + 4096);                              \
    gl_lds16(gsrc2 + (size_t)(t)*32, _b + 8192); }while(0)

    f32x4 acc[4][4];
#pragma unroll
    for(int m=0;m<4;m++)
#pragma unroll
        for(int n=0;n<4;n++)
            acc[m][n] = (f32x4){0.f,0.f,0.f,0.f};

    const int NT = K >> 5;
    STG(0);
    for(int t=0; t<NT; ++t){
        asm volatile("s_waitcnt vmcnt(0)" ::: "memory");
        __builtin_amdgcn_s_barrier();      // buf[t&1] resident for all waves
        __builtin_amdgcn_sched_barrier(0); // no reads hoisted above
        if(t+1 < NT) STG(t+1);             // WAR-safe: buf[t+1&1] reads done in t-1
        const int sb = (t&1)*12288;
        short8 af[4], bv[4];
#pragma unroll
        for(int mm=0; mm<4; ++mm)
            af[mm] = *(const short8*)&lds[sb + (wm*64 + mm*16 + fr)*32 + qa];
#pragma unroll
        for(int nf=0; nf<4; ++nf)
            bv[nf] = *(const short8*)&lds[sb + 8192 + (wn*64 + nf*16 + fr)*32 + qa];
        __builtin_amdgcn_s_setprio(1);
#pragma unroll
        for(int mm=0; mm<4; ++mm)
#pragma unroll
        for(int nf=0; nf<4; ++nf)
            acc[mm][nf] = __builtin_amdgcn_mfma_f32_16x16x32_bf16(
                af[mm], bv[nf], acc[mm][nf], 0,0,0);
        __builtin_amdgcn_s_setprio(0);
    }
#undef STG

#pragma unroll
    for(int m=0;m<4;m++)
#pragma unroll
        for(int n=0;n<4;n++){
            long col = brow0 + wn*64 + n*16 + fr;
#pragma unroll
            for(int j=0;j<4;j++){
                long row = arow0 + wm*64 + m*16 + fg*4 + j;
                C[row*(size_t)ldc + col] = f2b(acc[m][n][j]);
            }
        }
}

// ---------- RoPE + rank projection + gate (MFMA version) ----------
__global__ __launch_bounds__(256) void k_rope_proj(const ushort* __restrict__ qkvg,
                                                   const float* __restrict__ cosT,
                                                   const float* __restrict__ sinT,
                                                   const float* __restrict__ Wq,
                                                   const float* __restrict__ Wk,
                                                   const float* __restrict__ gb,
                                                   float* __restrict__ qr_s,
                                                   float* __restrict__ gk_s){
    __shared__ __align__(16) ushort lq[64*72], lk[64*72];
    __shared__ __align__(16) ushort wql[16*72], wkl[16*72];
    int tid = threadIdx.x, wid = tid >> 6, lane = tid & 63;
    int bt0 = blockIdx.x * 64;
    int h   = blockIdx.y;

    {
        int row = tid >> 4, seg = tid & 15;
        float4 wq4 = *(const float4*)(Wq + (size_t)h*1024 + row*64 + seg*4);
        float4 wk4 = *(const float4*)(Wk + (size_t)h*1024 + row*64 + seg*4);
        ushort* dq = &wql[row*72 + seg*4];
        ushort* dk = &wkl[row*72 + seg*4];
        dq[0]=f2b(wq4.x); dq[1]=f2b(wq4.y); dq[2]=f2b(wq4.z); dq[3]=f2b(wq4.w);
        dk[0]=f2b(wk4.x); dk[1]=f2b(wk4.y); dk[2]=f2b(wk4.z); dk[3]=f2b(wk4.w);
    }

#pragma unroll
    for(int rep=0; rep<2; ++rep){
        int flat = rep*256 + tid;
        int row = flat >> 3, seg = flat & 7;
        int t = (bt0 + row) & 2047;
        const ushort* base = qkvg + (size_t)(bt0+row)*NC_ + h*64 + seg*8;
        short8 q8 = *(const short8*)base;
        short8 k8 = *(const short8*)(base + 1024);
        float4 cv = *(const float4*)&cosT[t*32 + seg*4];
        float4 sv = *(const float4*)&sinT[t*32 + seg*4];
        float qf[8], kf[8];
#pragma unroll
        for(int j=0;j<8;j++){ qf[j]=b2f((ushort)q8[j]); kf[j]=b2f((ushort)k8[j]); }
        float c4[4] = {cv.x,cv.y,cv.z,cv.w};
        float s4[4] = {sv.x,sv.y,sv.z,sv.w};
        short8 qo, ko;
#pragma unroll
        for(int p=0;p<4;p++){
            float c=c4[p], s=s4[p];
            qo[2*p]   = (short)f2b(qf[2*p]*c - qf[2*p+1]*s);
            qo[2*p+1] = (short)f2b(qf[2*p]*s + qf[2*p+1]*c);
            ko[2*p]   = (short)f2b(kf[2*p]*c - kf[2*p+1]*s);
            ko[2*p+1] = (short)f2b(kf[2*p]*s + kf[2*p+1]*c);
        }
        *(short8*)&lq[row*72 + seg*8] = qo;
        *(short8*)&lk[row*72 + seg*8] = ko;
    }
    __syncthreads();

    int fr = lane & 15, fg = lane >> 4;
    int wrow = wid*16;
    short8 aq0 = *(const short8*)&lq[(wrow+fr)*72 + fg*8];
    short8 aq1 = *(const short8*)&lq[(wrow+fr)*72 + 32 + fg*8];
    short8 ak0 = *(const short8*)&lk[(wrow+fr)*72 + fg*8];
    short8 ak1 = *(const short8*)&lk[(wrow+fr)*72 + 32 + fg*8];
    short8 bq0 = *(const short8*)&wql[fr*72 + fg*8];
    short8 bq1 = *(const short8*)&wql[fr*72 + 32 + fg*8];
    short8 bk0 = *(const short8*)&wkl[fr*72 + fg*8];
    short8 bk1 = *(const short8*)&wkl[fr*72 + 32 + fg*8];
    f32x4 accq = (f32x4){0.f,0.f,0.f,0.f};
    f32x4 acck = (f32x4){0.f,0.f,0.f,0.f};
    accq = __builtin_amdgcn_mfma_f32_16x16x32_bf16(aq0, bq0, accq, 0,0,0);
    accq = __builtin_amdgcn_mfma_f32_16x16x32_bf16(aq1, bq1, accq, 0,0,0);
    acck = __builtin_amdgcn_mfma_f32_16x16x32_bf16(ak0, bk0, acck, 0,0,0);
    acck = __builtin_amdgcn_mfma_f32_16x16x32_bf16(ak1, bk1, acck, 0,0,0);

    int r = fr;
    float gbv = gb[h*16 + r];
#pragma unroll
    for(int j=0;j<4;j++){
        int bt = bt0 + wrow + fg*4 + j;
        int t  = bt & 2047, b = bt >> 11;
        size_t o = (((size_t)(b*16 + h))*2048 + t)*16 + r;
        qr_s[o] = accq[j];
        float gl = b2f(qkvg[(size_t)bt*NC_ + 3072 + h*16 + r]) + gbv;
        gk_s[o] = sigm(gl) * acck[j] * 0.125f;
    }
}

// ---------- scan pass 1 ----------
__global__ __launch_bounds__(64) void k_scan_local(const ushort* __restrict__ qkvg,
                                                   const float* __restrict__ gk_s,
                                                   const float* __restrict__ bdl,
                                                   float* __restrict__ Mloc){
    int lane = threadIdx.x;
    int bx = blockIdx.x;
    int ch = bx & (NCHUNK_-1), bh = bx >> 5;
    int b = bh >> 4, h = bh & 15;
    float dec[16], M[16];
#pragma unroll
    for(int r=0;r<16;r++){ dec[r] = sigm(bdl[h*16+r]); M[r] = 0.f; }

    int t0 = ch*CHUNK_;
    const float4*  gk4 = (const float4*)(gk_s + (((size_t)bh)*2048 + t0)*16);
    const ushort*  vp  = qkvg + ((size_t)(b*2048 + t0))*NC_ + 2048 + h*64 + lane;
    for(int tt=0; tt<CHUNK_; ++tt){
        float v = b2f(*vp); vp += NC_;
        float4 a0 = gk4[0], a1 = gk4[1], a2 = gk4[2], a3 = gk4[3]; gk4 += 4;
        float gk[16] = {a0.x,a0.y,a0.z,a0.w, a1.x,a1.y,a1.z,a1.w,
                        a2.x,a2.y,a2.z,a2.w, a3.x,a3.y,a3.z,a3.w};
#pragma unroll
        for(int r=0;r<16;r++) M[r] = fmaf(M[r], dec[r], gk[r]*v);
    }
    float* mp = Mloc + ((size_t)bx)*1024 + lane;
#pragma unroll
    for(int r=0;r<16;r++) mp[r*64] = M[r];
}

// ---------- scan pass 2 (in-place carry) ----------
__global__ __launch_bounds__(64) void k_scan_carry(float* __restrict__ Mloc,
                                                   const float* __restrict__ bdl){
    int lane = threadIdx.x;
    int sub = blockIdx.x & 3, bh = blockIdx.x >> 2, h = bh & 15;
    float decC[4], S[4];
#pragma unroll
    for(int rr=0;rr<4;rr++){
        decC[rr] = powf(sigm(bdl[h*16 + sub*4 + rr]), (float)CHUNK_);
        S[rr] = 0.f;
    }
    for(int c=0;c<NCHUNK_;c++){
        float* p = Mloc + ((size_t)(bh*NCHUNK_ + c))*1024 + lane + sub*4*64;
#pragma unroll
        for(int rr=0;rr<4;rr++){
            float m = p[rr*64];
            p[rr*64] = S[rr];
            S[rr] = fmaf(S[rr], decC[rr], m);
        }
    }
}

// ---------- scan pass 3 ----------
__global__ __launch_bounds__(64) void k_scan_out(const ushort* __restrict__ qkvg,
                                                 const float* __restrict__ gk_s,
                                                 const float* __restrict__ qr_s,
                                                 const float* __restrict__ Mst,
                                                 const float* __restrict__ bdl,
                                                 ushort* __restrict__ Ybf){
    int lane = threadIdx.x;
    int bx = blockIdx.x;
    int ch = bx & (NCHUNK_-1), bh = bx >> 5;
    int b = bh >> 4, h = bh & 15;
    float dec[16], M[16];
#pragma unroll
    for(int r=0;r<16;r++) dec[r] = sigm(bdl[h*16+r]);
    const float* sp = Mst + ((size_t)bx)*1024 + lane;
#pragma unroll
    for(int r=0;r<16;r++) M[r] = sp[r*64];

    int t0 = ch*CHUNK_;
    const float4* gk4 = (const float4*)(gk_s + (((size_t)bh)*2048 + t0)*16);
    const float4* q4  = (const float4*)(qr_s + (((size_t)bh)*2048 + t0)*16);
    const ushort* vp  = qkvg + ((size_t)(b*2048 + t0))*NC_ + 2048 + h*64 + lane;
    ushort*       yp  = Ybf  + ((size_t)(b*2048 + t0))*1024 + h*64 + lane;
    for(int tt=0; tt<CHUNK_; ++tt){
        float v = b2f(*vp); vp += NC_;
        float4 a0 = gk4[0], a1 = gk4[1], a2 = gk4[2], a3 = gk4[3]; gk4 += 4;
        float4 b0 = q4[0],  b1 = q4[1],  b2 = q4[2],  b3 = q4[3];  q4  += 4;
        float gk[16] = {a0.x,a0.y,a0.z,a0.w, a1.x,a1.y,a1.z,a1.w,
                        a2.x,a2.y,a2.z,a2.w, a3.x,a3.y,a3.z,a3.w};
        float qv[16] = {b0.x,b0.y,b0.z,b0.w, b1.x,b1.y,b1.z,b1.w,
                        b2.x,b2.y,b2.z,b2.w, b3.x,b3.y,b3.z,b3.w};
        float y = 0.f;
#pragma unroll
        for(int r=0;r<16;r++){
            M[r] = fmaf(M[r], dec[r], gk[r]*v);
            y    = fmaf(qv[r], M[r], y);
        }
        *yp = f2b(y); yp += 1024;
    }
}

// ---------- residual + LayerNorm ----------
__global__ __launch_bounds__(256) void k_ln(const float* __restrict__ x,
                                            const ushort* __restrict__ O,
                                            const float* __restrict__ ob,
                                            const float* __restrict__ lg,
                                            const float* __restrict__ lb,
                                            float* __restrict__ out){
    __shared__ float red[8];
    int row = blockIdx.x, tid = threadIdx.x;
    float hv[4];
    float sum = 0.f, ssq = 0.f;
#pragma unroll
    for(int k2=0;k2<4;k2++){
        int j = tid + k2*256;
        float v = x[(size_t)row*1024 + j] + b2f(O[(size_t)row*1024 + j]) + ob[j];
        hv[k2] = v; sum += v; ssq += v*v;
    }
#pragma unroll
    for(int off=32; off; off >>= 1){
        sum += __shfl_down(sum, off, 64);
        ssq += __shfl_down(ssq, off, 64);
    }
    int wid = tid >> 6, lane = tid & 63;
    if(lane == 0){ red[wid] = sum; red[4+wid] = ssq; }
    __syncthreads();
    if(tid == 0){
        float s = red[0]+red[1]+red[2]+red[3];
        float q = red[4]+red[5]+red[6]+red[7];
        float mu = s / 1024.f;
        red[0] = mu;
        red[1] = q / 1024.f - mu*mu;
    }
    __syncthreads();
    float mu = red[0];
    float inv = rsqrtf(red[1] + 1e-5f);
#pragma unroll
    for(int k2=0;k2<4;k2++){
        int j = tid + k2*256;
        out[(size_t)row*1024 + j] = (hv[k2]-mu)*inv*lg[j] + lb[j];
    }
}

extern "C" void kernel_launch(void* const* d_in, const int* in_sizes, int n_in,
                              void* d_out, int out_size, void* d_ws, size_t ws_size,
                              hipStream_t stream){
    const float* x    = (const float*)d_in[0];
    const float* q_w  = (const float*)d_in[1];
    const float* k_w  = (const float*)d_in[2];
    const float* v_w  = (const float*)d_in[3];
    const float* Wq   = (const float*)d_in[4];
    const float* Wk   = (const float*)d_in[5];
    const float* g_w  = (const float*)d_in[6];
    const float* g_b  = (const float*)d_in[7];
    const float* bdl  = (const float*)d_in[8];
    const float* outw = (const float*)d_in[9];
    const float* outb = (const float*)d_in[10];
    const float* ln_g = (const float*)d_in[11];
    const float* ln_b = (const float*)d_in[12];
    float* out = (float*)d_out;

    char* ws = (char*)d_ws;
    size_t off = 0;
    ushort* xbf  = (ushort*)(ws + off); off += (size_t)BT_*HS_*2;
    ushort* wcat = (ushort*)(ws + off); off += (size_t)NC_*HS_*2;
    ushort* owbf = (ushort*)(ws + off); off += (size_t)HS_*HS_*2;
    float*  cosT = (float*)(ws + off);  off += (size_t)T_*32*4;
    float*  sinT = (float*)(ws + off);  off += (size_t)T_*32*4;
    ushort* qkvg = (ushort*)(ws + off); off += (size_t)BT_*NC_*2;
    float*  qr_s = (float*)(ws + off);  off += (size_t)BT_*H_*R_*4;
    float*  gk_s = (float*)(ws + off);  off += (size_t)BT_*H_*R_*4;
    float*  Mloc = (float*)(ws + off);  off += (size_t)B_*H_*NCHUNK_*R_*D_*4;
    ushort* Ybf = xbf;     // xbf dead after GEMM1
    ushort* O   = qkvg;    // qkvg dead after scan

    // merged prep (x cast | wcat build | outw cast | rope table)
    k_prep<<<12800, 256, 0, stream>>>(x, q_w, k_w, v_w, g_w, outw,
                                      xbf, wcat, owbf, cosT, sinT);

    // GEMM1: qkvg[8192][3328] = xbf @ wcat^T   (256x128 dbuf, 32x26=832 blocks)
    k_gemm256d<<<dim3(BT_/256, NC_/128), 512, 0, stream>>>(xbf, wcat, qkvg, HS_, NC_);

    // rope + rank-proj + gate (MFMA)
    k_rope_proj<<<dim3(BT_/64, H_), 256, 0, stream>>>(qkvg, cosT, sinT, Wq, Wk, g_b, qr_s, gk_s);

    // chunked scan (split 3-pass: 2048 independent 1-wave blocks = TLP)
    k_scan_local<<<B_*H_*NCHUNK_, 64, 0, stream>>>(qkvg, gk_s, bdl, Mloc);
    k_scan_carry<<<B_*H_*4, 64, 0, stream>>>(Mloc, bdl);
    k_scan_out<<<B_*H_*NCHUNK_, 64, 0, stream>>>(qkvg, gk_s, qr_s, Mloc, bdl, Ybf);

    // GEMM2: O[8192][1024] = Ybf @ owbf^T  (32x8=256 blocks)
    k_gemm256d<<<dim3(BT_/256, HS_/128), 512, 0, stream>>>(Ybf, owbf, O, HS_, HS_);

    // residual + LayerNorm
    k_ln<<<BT_, 256, 0, stream>>>(x, O, outb, ln_g, ln_b, out);

    (void)in_sizes; (void)n_in; (void)out_size; (void)ws_size;
}

// Round 15
// 187.659 us; speedup vs baseline: 1.6685x; 1.0236x over previous
//
#include <hip/hip_runtime.h>
#include <hip/hip_bf16.h>

#define B_ 4
#define T_ 2048
#define HS_ 1024
#define H_ 16
#define R_ 16
#define D_ 64
#define BT_ (B_*T_)          // 8192
#define NC_ 3328             // q(1024) k(1024) v(1024) g(256)
#define CHUNK_ 64
#define NCHUNK_ (T_/CHUNK_)  // 32

typedef __attribute__((ext_vector_type(8))) short short8;
typedef __attribute__((ext_vector_type(4))) float f32x4;

__device__ __forceinline__ float b2f(ushort u){
    union{unsigned int i; float f;} v; v.i = ((unsigned int)u) << 16; return v.f;
}
__device__ __forceinline__ ushort f2b(float f){
    __hip_bfloat16 h = __float2bfloat16(f);
    return *reinterpret_cast<ushort*>(&h);
}
__device__ __forceinline__ float sigm(float x){ return 1.f/(1.f+expf(-x)); }

// async global->LDS, 16B per lane; lds dest is wave-uniform base + lane*16
__device__ __forceinline__ void gl_lds16(const void* g, void* l){
    __builtin_amdgcn_global_load_lds((const __attribute__((address_space(1))) void*)g,
                                     (__attribute__((address_space(3))) void*)l,
                                     16, 0, 0);
}

// ---------- merged prep kernel ----------
__global__ void k_prep(const float* __restrict__ x,
                       const float* __restrict__ qw, const float* __restrict__ kw,
                       const float* __restrict__ vw, const float* __restrict__ gw,
                       const float* __restrict__ outw,
                       ushort* __restrict__ xbf, ushort* __restrict__ wcat,
                       ushort* __restrict__ owbf,
                       float* __restrict__ cosT, float* __restrict__ sinT){
    int bid = blockIdx.x;
    if(bid < 8192){
        int i = bid*256 + threadIdx.x;
        float4 v = ((const float4*)x)[i];
        ushort4 o; o.x=f2b(v.x); o.y=f2b(v.y); o.z=f2b(v.z); o.w=f2b(v.w);
        ((ushort4*)xbf)[i] = o;
    } else if(bid < 11520){
        int i = (bid-8192)*256 + threadIdx.x;
        int e = i*4;
        int row = e >> 10, col = e & 1023;
        const float* src;
        if      (row < 1024) src = qw + (size_t)row*1024 + col;
        else if (row < 2048) src = kw + (size_t)(row-1024)*1024 + col;
        else if (row < 3072) src = vw + (size_t)(row-2048)*1024 + col;
        else                 src = gw + (size_t)(row-3072)*1024 + col;
        float4 v = *(const float4*)src;
        ushort4 o; o.x=f2b(v.x); o.y=f2b(v.y); o.z=f2b(v.z); o.w=f2b(v.w);
        ((ushort4*)wcat)[i] = o;
    } else if(bid < 12544){
        int i = (bid-11520)*256 + threadIdx.x;
        float4 v = ((const float4*)outw)[i];
        ushort4 o; o.x=f2b(v.x); o.y=f2b(v.y); o.z=f2b(v.z); o.w=f2b(v.w);
        ((ushort4*)owbf)[i] = o;
    } else {
        int i = (bid-12544)*256 + threadIdx.x;   // 65536 = 2048*32
        int t = i >> 5, f = i & 31;
        float inv = powf(10000.f, -(float)f/32.f);
        float a = (float)t * inv;
        cosT[i] = cosf(a);
        sinT[i] = sinf(a);
    }
}

// ---------- 256x128 dbuf bf16 GEMM: C = A @ B^T (best measured, GEMM1) ----------
// 8 waves (4M x 2N), per-wave 64x64. BK=32, LDS 48KB dbuf, 3 blocks/CU.
// Bank rotation (fg+(fr>>1))&3 + inverse-staged source: measured 0 conflicts.
__global__ __launch_bounds__(512, 4) void k_gemm256d(const ushort* __restrict__ A,
                                                     const ushort* __restrict__ Bm,
                                                     ushort* __restrict__ C,
                                                     int K, int ldc){
    __shared__ __align__(16) ushort lds[24576];   // 2 x 12288 ushorts (48KB)
    const int tid  = threadIdx.x;
    const int lane = tid & 63, w = tid >> 6;
    const int fr = lane & 15, fg = lane >> 4;
    const int wm = w >> 1, wn = w & 1;            // 4M x 2N
    const int qa = ((fg + (fr >> 1)) & 3) * 8;    // verified rotation (ushorts)

    // XCD supertile mapping (R5: keeps A-panel resident in XCD L2)
    int mt = gridDim.x;
    int L = blockIdx.y * mt + blockIdx.x;
    int bxi, byi;
    int msub = mt >> 3;
    if((mt & 7) == 0 && msub > 0){
        int xcd = L & 7, c = L >> 3;
        bxi = xcd * msub + (c % msub);
        byi = c / msub;
    } else { bxi = blockIdx.x; byi = blockIdx.y; }
    const long arow0 = (long)bxi * 256;
    const long brow0 = (long)byi * 128;

    const int srow = tid >> 2;
    const int scol = ((((tid & 3) - (tid >> 3)) & 3)) * 8;
    const ushort* gsrc0 = A  + (arow0 +       srow) * (size_t)K + scol;
    const ushort* gsrc1 = A  + (arow0 + 128 + srow) * (size_t)K + scol;
    const ushort* gsrc2 = Bm + (brow0 +       srow) * (size_t)K + scol;

#define STG(t) do{ ushort* _b = &lds[((t)&1)*12288 + w*512];                  \
    gl_lds16(gsrc0 + (size_t)(t)*32, _b);                                     \
    gl_lds16(gsrc1 + (size_t)(t)*32, _b + 4096);                              \
    gl_lds16(gsrc2 + (size_t)(t)*32, _b + 8192); }while(0)

    f32x4 acc[4][4];
#pragma unroll
    for(int m=0;m<4;m++)
#pragma unroll
        for(int n=0;n<4;n++)
            acc[m][n] = (f32x4){0.f,0.f,0.f,0.f};

    const int NT = K >> 5;
    STG(0);
    for(int t=0; t<NT; ++t){
        asm volatile("s_waitcnt vmcnt(0)" ::: "memory");
        __builtin_amdgcn_s_barrier();      // buf[t&1] resident for all waves
        __builtin_amdgcn_sched_barrier(0); // no reads hoisted above
        if(t+1 < NT) STG(t+1);             // WAR-safe: buf[t+1&1] reads done in t-1
        const int sb = (t&1)*12288;
        short8 af[4], bv[4];
#pragma unroll
        for(int mm=0; mm<4; ++mm)
            af[mm] = *(const short8*)&lds[sb + (wm*64 + mm*16 + fr)*32 + qa];
#pragma unroll
        for(int nf=0; nf<4; ++nf)
            bv[nf] = *(const short8*)&lds[sb + 8192 + (wn*64 + nf*16 + fr)*32 + qa];
        __builtin_amdgcn_s_setprio(1);
#pragma unroll
        for(int mm=0; mm<4; ++mm)
#pragma unroll
        for(int nf=0; nf<4; ++nf)
            acc[mm][nf] = __builtin_amdgcn_mfma_f32_16x16x32_bf16(
                af[mm], bv[nf], acc[mm][nf], 0,0,0);
        __builtin_amdgcn_s_setprio(0);
    }
#undef STG

#pragma unroll
    for(int m=0;m<4;m++)
#pragma unroll
        for(int n=0;n<4;n++){
            long col = brow0 + wn*64 + n*16 + fr;
#pragma unroll
            for(int j=0;j<4;j++){
                long row = arow0 + wm*64 + m*16 + fg*4 + j;
                C[row*(size_t)ldc + col] = f2b(acc[m][n][j]);
            }
        }
}

// ---------- 128x128 dbuf bf16 GEMM (GEMM2: 512 blocks -> 2+/CU overlap) ----------
// 4 waves (2M x 2N), per-wave 64x64. BK=32, LDS 32KB dbuf (4-5 blocks/CU).
// Same rotation/staging algebra as k_gemm256d (f(row)=row>>1 row-count-free).
__global__ __launch_bounds__(256, 4) void k_gemm128d(const ushort* __restrict__ A,
                                                     const ushort* __restrict__ Bm,
                                                     ushort* __restrict__ C,
                                                     int K, int ldc){
    __shared__ __align__(16) ushort lds[16384];   // 2 x 8192 ushorts (32KB)
    const int tid  = threadIdx.x;
    const int lane = tid & 63, w = tid >> 6;
    const int fr = lane & 15, fg = lane >> 4;
    const int wm = w >> 1, wn = w & 1;            // 2M x 2N
    const int qa = ((fg + (fr >> 1)) & 3) * 8;

    int mt = gridDim.x;
    int L = blockIdx.y * mt + blockIdx.x;
    int bxi, byi;
    int msub = mt >> 3;
    if((mt & 7) == 0 && msub > 0){
        int xcd = L & 7, c = L >> 3;
        bxi = xcd * msub + (c % msub);
        byi = c / msub;
    } else { bxi = blockIdx.x; byi = blockIdx.y; }
    const long arow0 = (long)bxi * 128;
    const long brow0 = (long)byi * 128;

    const int srow = tid >> 2;                     // 0..63
    const int scol = ((((tid & 3) - (tid >> 3)) & 3)) * 8;
    const ushort* gsrc0 = A  + (arow0 +      srow) * (size_t)K + scol;
    const ushort* gsrc1 = A  + (arow0 + 64 + srow) * (size_t)K + scol;
    const ushort* gsrc2 = Bm + (brow0 +      srow) * (size_t)K + scol;
    const ushort* gsrc3 = Bm + (brow0 + 64 + srow) * (size_t)K + scol;

#define STG(t) do{ ushort* _b = &lds[((t)&1)*8192 + w*512];                   \
    gl_lds16(gsrc0 + (size_t)(t)*32, _b);                                     \
    gl_lds16(gsrc1 + (size_t)(t)*32, _b + 2048);                              \
    gl_lds16(gsrc2 + (size_t)(t)*32, _b + 4096);                              \
    gl_lds16(gsrc3 + (size_t)(t)*32, _b + 6144); }while(0)

    f32x4 acc[4][4];
#pragma unroll
    for(int m=0;m<4;m++)
#pragma unroll
        for(int n=0;n<4;n++)
            acc[m][n] = (f32x4){0.f,0.f,0.f,0.f};

    const int NT = K >> 5;
    STG(0);
    for(int t=0; t<NT; ++t){
        asm volatile("s_waitcnt vmcnt(0)" ::: "memory");
        __builtin_amdgcn_s_barrier();
        __builtin_amdgcn_sched_barrier(0);
        if(t+1 < NT) STG(t+1);
        const int sb = (t&1)*8192;
        short8 af[4], bv[4];
#pragma unroll
        for(int mm=0; mm<4; ++mm)
            af[mm] = *(const short8*)&lds[sb + (wm*64 + mm*16 + fr)*32 + qa];
#pragma unroll
        for(int nf=0; nf<4; ++nf)
            bv[nf] = *(const short8*)&lds[sb + 4096 + (wn*64 + nf*16 + fr)*32 + qa];
        __builtin_amdgcn_s_setprio(1);
#pragma unroll
        for(int mm=0; mm<4; ++mm)
#pragma unroll
        for(int nf=0; nf<4; ++nf)
            acc[mm][nf] = __builtin_amdgcn_mfma_f32_16x16x32_bf16(
                af[mm], bv[nf], acc[mm][nf], 0,0,0);
        __builtin_amdgcn_s_setprio(0);
    }
#undef STG

#pragma unroll
    for(int m=0;m<4;m++)
#pragma unroll
        for(int n=0;n<4;n++){
            long col = brow0 + wn*64 + n*16 + fr;
#pragma unroll
            for(int j=0;j<4;j++){
                long row = arow0 + wm*64 + m*16 + fg*4 + j;
                C[row*(size_t)ldc + col] = f2b(acc[m][n][j]);
            }
        }
}

// ---------- RoPE + rank projection + gate (MFMA version) ----------
__global__ __launch_bounds__(256) void k_rope_proj(const ushort* __restrict__ qkvg,
                                                   const float* __restrict__ cosT,
                                                   const float* __restrict__ sinT,
                                                   const float* __restrict__ Wq,
                                                   const float* __restrict__ Wk,
                                                   const float* __restrict__ gb,
                                                   float* __restrict__ qr_s,
                                                   float* __restrict__ gk_s){
    __shared__ __align__(16) ushort lq[64*72], lk[64*72];
    __shared__ __align__(16) ushort wql[16*72], wkl[16*72];
    int tid = threadIdx.x, wid = tid >> 6, lane = tid & 63;
    int bt0 = blockIdx.x * 64;
    int h   = blockIdx.y;

    {
        int row = tid >> 4, seg = tid & 15;
        float4 wq4 = *(const float4*)(Wq + (size_t)h*1024 + row*64 + seg*4);
        float4 wk4 = *(const float4*)(Wk + (size_t)h*1024 + row*64 + seg*4);
        ushort* dq = &wql[row*72 + seg*4];
        ushort* dk = &wkl[row*72 + seg*4];
        dq[0]=f2b(wq4.x); dq[1]=f2b(wq4.y); dq[2]=f2b(wq4.z); dq[3]=f2b(wq4.w);
        dk[0]=f2b(wk4.x); dk[1]=f2b(wk4.y); dk[2]=f2b(wk4.z); dk[3]=f2b(wk4.w);
    }

#pragma unroll
    for(int rep=0; rep<2; ++rep){
        int flat = rep*256 + tid;
        int row = flat >> 3, seg = flat & 7;
        int t = (bt0 + row) & 2047;
        const ushort* base = qkvg + (size_t)(bt0+row)*NC_ + h*64 + seg*8;
        short8 q8 = *(const short8*)base;
        short8 k8 = *(const short8*)(base + 1024);
        float4 cv = *(const float4*)&cosT[t*32 + seg*4];
        float4 sv = *(const float4*)&sinT[t*32 + seg*4];
        float qf[8], kf[8];
#pragma unroll
        for(int j=0;j<8;j++){ qf[j]=b2f((ushort)q8[j]); kf[j]=b2f((ushort)k8[j]); }
        float c4[4] = {cv.x,cv.y,cv.z,cv.w};
        float s4[4] = {sv.x,sv.y,sv.z,sv.w};
        short8 qo, ko;
#pragma unroll
        for(int p=0;p<4;p++){
            float c=c4[p], s=s4[p];
            qo[2*p]   = (short)f2b(qf[2*p]*c - qf[2*p+1]*s);
            qo[2*p+1] = (short)f2b(qf[2*p]*s + qf[2*p+1]*c);
            ko[2*p]   = (short)f2b(kf[2*p]*c - kf[2*p+1]*s);
            ko[2*p+1] = (short)f2b(kf[2*p]*s + kf[2*p+1]*c);
        }
        *(short8*)&lq[row*72 + seg*8] = qo;
        *(short8*)&lk[row*72 + seg*8] = ko;
    }
    __syncthreads();

    int fr = lane & 15, fg = lane >> 4;
    int wrow = wid*16;
    short8 aq0 = *(const short8*)&lq[(wrow+fr)*72 + fg*8];
    short8 aq1 = *(const short8*)&lq[(wrow+fr)*72 + 32 + fg*8];
    short8 ak0 = *(const short8*)&lk[(wrow+fr)*72 + fg*8];
    short8 ak1 = *(const short8*)&lk[(wrow+fr)*72 + 32 + fg*8];
    short8 bq0 = *(const short8*)&wql[fr*72 + fg*8];
    short8 bq1 = *(const short8*)&wql[fr*72 + 32 + fg*8];
    short8 bk0 = *(const short8*)&wkl[fr*72 + fg*8];
    short8 bk1 = *(const short8*)&wkl[fr*72 + 32 + fg*8];
    f32x4 accq = (f32x4){0.f,0.f,0.f,0.f};
    f32x4 acck = (f32x4){0.f,0.f,0.f,0.f};
    accq = __builtin_amdgcn_mfma_f32_16x16x32_bf16(aq0, bq0, accq, 0,0,0);
    accq = __builtin_amdgcn_mfma_f32_16x16x32_bf16(aq1, bq1, accq, 0,0,0);
    acck = __builtin_amdgcn_mfma_f32_16x16x32_bf16(ak0, bk0, acck, 0,0,0);
    acck = __builtin_amdgcn_mfma_f32_16x16x32_bf16(ak1, bk1, acck, 0,0,0);

    int r = fr;
    float gbv = gb[h*16 + r];
#pragma unroll
    for(int j=0;j<4;j++){
        int bt = bt0 + wrow + fg*4 + j;
        int t  = bt & 2047, b = bt >> 11;
        size_t o = (((size_t)(b*16 + h))*2048 + t)*16 + r;
        qr_s[o] = accq[j];
        float gl = b2f(qkvg[(size_t)bt*NC_ + 3072 + h*16 + r]) + gbv;
        gk_s[o] = sigm(gl) * acck[j] * 0.125f;
    }
}

// ---------- scan pass 1 ----------
__global__ __launch_bounds__(64) void k_scan_local(const ushort* __restrict__ qkvg,
                                                   const float* __restrict__ gk_s,
                                                   const float* __restrict__ bdl,
                                                   float* __restrict__ Mloc){
    int lane = threadIdx.x;
    int bx = blockIdx.x;
    int ch = bx & (NCHUNK_-1), bh = bx >> 5;
    int b = bh >> 4, h = bh & 15;
    float dec[16], M[16];
#pragma unroll
    for(int r=0;r<16;r++){ dec[r] = sigm(bdl[h*16+r]); M[r] = 0.f; }

    int t0 = ch*CHUNK_;
    const float4*  gk4 = (const float4*)(gk_s + (((size_t)bh)*2048 + t0)*16);
    const ushort*  vp  = qkvg + ((size_t)(b*2048 + t0))*NC_ + 2048 + h*64 + lane;
    for(int tt=0; tt<CHUNK_; ++tt){
        float v = b2f(*vp); vp += NC_;
        float4 a0 = gk4[0], a1 = gk4[1], a2 = gk4[2], a3 = gk4[3]; gk4 += 4;
        float gk[16] = {a0.x,a0.y,a0.z,a0.w, a1.x,a1.y,a1.z,a1.w,
                        a2.x,a2.y,a2.z,a2.w, a3.x,a3.y,a3.z,a3.w};
#pragma unroll
        for(int r=0;r<16;r++) M[r] = fmaf(M[r], dec[r], gk[r]*v);
    }
    float* mp = Mloc + ((size_t)bx)*1024 + lane;
#pragma unroll
    for(int r=0;r<16;r++) mp[r*64] = M[r];
}

// ---------- scan pass 2 (in-place carry, batch-prefetch, 1 r per block) ----------
__global__ __launch_bounds__(64) void k_scan_carry(float* __restrict__ Mloc,
                                                   const float* __restrict__ bdl){
    int lane = threadIdx.x;
    int r = blockIdx.x & 15, bh = blockIdx.x >> 4, h = bh & 15;
    float dc = powf(sigm(bdl[h*16 + r]), (float)CHUNK_);
    float S = 0.f;
    size_t base = (size_t)bh*NCHUNK_*1024 + r*64 + lane;
    for(int cb=0; cb<NCHUNK_; cb+=8){
        float m[8];
#pragma unroll
        for(int c=0;c<8;c++) m[c] = Mloc[base + (size_t)(cb+c)*1024];
#pragma unroll
        for(int c=0;c<8;c++){
            Mloc[base + (size_t)(cb+c)*1024] = S;
            S = fmaf(S, dc, m[c]);
        }
    }
}

// ---------- scan pass 3 ----------
__global__ __launch_bounds__(64) void k_scan_out(const ushort* __restrict__ qkvg,
                                                 const float* __restrict__ gk_s,
                                                 const float* __restrict__ qr_s,
                                                 const float* __restrict__ Mst,
                                                 const float* __restrict__ bdl,
                                                 ushort* __restrict__ Ybf){
    int lane = threadIdx.x;
    int bx = blockIdx.x;
    int ch = bx & (NCHUNK_-1), bh = bx >> 5;
    int b = bh >> 4, h = bh & 15;
    float dec[16], M[16];
#pragma unroll
    for(int r=0;r<16;r++) dec[r] = sigm(bdl[h*16+r]);
    const float* sp = Mst + ((size_t)bx)*1024 + lane;
#pragma unroll
    for(int r=0;r<16;r++) M[r] = sp[r*64];

    int t0 = ch*CHUNK_;
    const float4* gk4 = (const float4*)(gk_s + (((size_t)bh)*2048 + t0)*16);
    const float4* q4  = (const float4*)(qr_s + (((size_t)bh)*2048 + t0)*16);
    const ushort* vp  = qkvg + ((size_t)(b*2048 + t0))*NC_ + 2048 + h*64 + lane;
    ushort*       yp  = Ybf  + ((size_t)(b*2048 + t0))*1024 + h*64 + lane;
    for(int tt=0; tt<CHUNK_; ++tt){
        float v = b2f(*vp); vp += NC_;
        float4 a0 = gk4[0], a1 = gk4[1], a2 = gk4[2], a3 = gk4[3]; gk4 += 4;
        float4 b0 = q4[0],  b1 = q4[1],  b2 = q4[2],  b3 = q4[3];  q4  += 4;
        float gk[16] = {a0.x,a0.y,a0.z,a0.w, a1.x,a1.y,a1.z,a1.w,
                        a2.x,a2.y,a2.z,a2.w, a3.x,a3.y,a3.z,a3.w};
        float qv[16] = {b0.x,b0.y,b0.z,b0.w, b1.x,b1.y,b1.z,b1.w,
                        b2.x,b2.y,b2.z,b2.w, b3.x,b3.y,b3.z,b3.w};
        float y = 0.f;
#pragma unroll
        for(int r=0;r<16;r++){
            M[r] = fmaf(M[r], dec[r], gk[r]*v);
            y    = fmaf(qv[r], M[r], y);
        }
        *yp = f2b(y); yp += 1024;
    }
}

// ---------- residual + LayerNorm ----------
__global__ __launch_bounds__(256) void k_ln(const float* __restrict__ x,
                                            const ushort* __restrict__ O,
                                            const float* __restrict__ ob,
                                            const float* __restrict__ lg,
                                            const float* __restrict__ lb,
                                            float* __restrict__ out){
    __shared__ float red[8];
    int row = blockIdx.x, tid = threadIdx.x;
    float hv[4];
    float sum = 0.f, ssq = 0.f;
#pragma unroll
    for(int k2=0;k2<4;k2++){
        int j = tid + k2*256;
        float v = x[(size_t)row*1024 + j] + b2f(O[(size_t)row*1024 + j]) + ob[j];
        hv[k2] = v; sum += v; ssq += v*v;
    }
#pragma unroll
    for(int off=32; off; off >>= 1){
        sum += __shfl_down(sum, off, 64);
        ssq += __shfl_down(ssq, off, 64);
    }
    int wid = tid >> 6, lane = tid & 63;
    if(lane == 0){ red[wid] = sum; red[4+wid] = ssq; }
    __syncthreads();
    if(tid == 0){
        float s = red[0]+red[1]+red[2]+red[3];
        float q = red[4]+red[5]+red[6]+red[7];
        float mu = s / 1024.f;
        red[0] = mu;
        red[1] = q / 1024.f - mu*mu;
    }
    __syncthreads();
    float mu = red[0];
    float inv = rsqrtf(red[1] + 1e-5f);
#pragma unroll
    for(int k2=0;k2<4;k2++){
        int j = tid + k2*256;
        out[(size_t)row*1024 + j] = (hv[k2]-mu)*inv*lg[j] + lb[j];
    }
}

extern "C" void kernel_launch(void* const* d_in, const int* in_sizes, int n_in,
                              void* d_out, int out_size, void* d_ws, size_t ws_size,
                              hipStream_t stream){
    const float* x    = (const float*)d_in[0];
    const float* q_w  = (const float*)d_in[1];
    const float* k_w  = (const float*)d_in[2];
    const float* v_w  = (const float*)d_in[3];
    const float* Wq   = (const float*)d_in[4];
    const float* Wk   = (const float*)d_in[5];
    const float* g_w  = (const float*)d_in[6];
    const float* g_b  = (const float*)d_in[7];
    const float* bdl  = (const float*)d_in[8];
    const float* outw = (const float*)d_in[9];
    const float* outb = (const float*)d_in[10];
    const float* ln_g = (const float*)d_in[11];
    const float* ln_b = (const float*)d_in[12];
    float* out = (float*)d_out;

    char* ws = (char*)d_ws;
    size_t off = 0;
    ushort* xbf  = (ushort*)(ws + off); off += (size_t)BT_*HS_*2;
    ushort* wcat = (ushort*)(ws + off); off += (size_t)NC_*HS_*2;
    ushort* owbf = (ushort*)(ws + off); off += (size_t)HS_*HS_*2;
    float*  cosT = (float*)(ws + off);  off += (size_t)T_*32*4;
    float*  sinT = (float*)(ws + off);  off += (size_t)T_*32*4;
    ushort* qkvg = (ushort*)(ws + off); off += (size_t)BT_*NC_*2;
    float*  qr_s = (float*)(ws + off);  off += (size_t)BT_*H_*R_*4;
    float*  gk_s = (float*)(ws + off);  off += (size_t)BT_*H_*R_*4;
    float*  Mloc = (float*)(ws + off);  off += (size_t)B_*H_*NCHUNK_*R_*D_*4;
    ushort* Ybf = xbf;     // xbf dead after GEMM1
    ushort* O   = qkvg;    // qkvg dead after scan

    // merged prep (x cast | wcat build | outw cast | rope table)
    k_prep<<<12800, 256, 0, stream>>>(x, q_w, k_w, v_w, g_w, outw,
                                      xbf, wcat, owbf, cosT, sinT);

    // GEMM1: qkvg[8192][3328] = xbf @ wcat^T   (256x128 dbuf, 32x26=832 blocks)
    k_gemm256d<<<dim3(BT_/256, NC_/128), 512, 0, stream>>>(xbf, wcat, qkvg, HS_, NC_);

    // rope + rank-proj + gate (MFMA)
    k_rope_proj<<<dim3(BT_/64, H_), 256, 0, stream>>>(qkvg, cosT, sinT, Wq, Wk, g_b, qr_s, gk_s);

    // chunked scan (split 3-pass)
    k_scan_local<<<B_*H_*NCHUNK_, 64, 0, stream>>>(qkvg, gk_s, bdl, Mloc);
    k_scan_carry<<<B_*H_*16, 64, 0, stream>>>(Mloc, bdl);
    k_scan_out<<<B_*H_*NCHUNK_, 64, 0, stream>>>(qkvg, gk_s, qr_s, Mloc, bdl, Ybf);

    // GEMM2: O[8192][1024] = Ybf @ owbf^T  (128x128, 64x8=512 blocks, 2+/CU)
    k_gemm128d<<<dim3(BT_/128, HS_/128), 256, 0, stream>>>(Ybf, owbf, O, HS_, HS_);

    // residual + LayerNorm
    k_ln<<<BT_, 256, 0, stream>>>(x, O, outb, ln_g, ln_b, out);

    (void)in_sizes; (void)n_in; (void)out_size; (void)ws_size;
}